// Round 8
// baseline (313.990 us; speedup 1.0000x reference)
//
#include <hip/hip_runtime.h>
#include <hip/hip_bf16.h>

// Self-attention: B=4, S=2048, D=768, fp32 in/out, bf16 MFMA internally.
// R14: fused Es+PV v2. R13's fused kernel was latency-dead (MfmaUtil 10.7%,
// 195us) from gather line-waste: V B-frags hit 64 lines/instr, K 16; line
// model (491K lines/CU @ ~1/cyc = 205us) matched measured 195. v2 fixes the
// plumbing, same verified math:
//   - K staged via glds16 (proven swizzled-GEMM pattern, perfect 8 lines/KB):
//     KVBLK=256 x BK=64 double-buffered d-loop, 2-phase barriers.
//   - PV in O^T form (A=V rows=e, B=P rows=q): V A-frag = contiguous 16B/lane
//     (16 lines/instr, L1-reused across k-slices).
//   - Q in XOR-swizzled 64-short-row chunks (R13's 776-pad aliased 8-way).
//   - Cross-stage pipeline: d-loop of kv-tile t+1 interleaves PV chunks of
//     tile t (disjoint LDS) -> ~20 MFMA/barrier-pair, V latency hidden.
// LDS 128 KiB exactly: Qs 48K | Ks 2x16K... (2x32K) | Ps 16K. 256 blocks.
// QKV stays 128x128 2-phase + XCD swizzle; prep unchanged.
// ws: Xb | WqT WkT WvT | Qb Kb Vt

typedef __attribute__((ext_vector_type(8))) short short8;
typedef __attribute__((ext_vector_type(4))) short short4v;
typedef __attribute__((ext_vector_type(4))) float float4v;

static constexpr int B_ = 4, S_ = 2048, D_ = 768;
static constexpr int MS = B_ * S_;  // 8192

__device__ inline short f2bf(float f) {
  __hip_bfloat16 h = __float2bfloat16(f);
  union { __hip_bfloat16 h; short s; } u; u.h = h; return u.s;
}

typedef const __attribute__((address_space(1))) unsigned int g_u32;
typedef __attribute__((address_space(3))) unsigned int l_u32;

__device__ __forceinline__ void glds16(const short* g, short* l) {
  __builtin_amdgcn_global_load_lds((g_u32*)g, (l_u32*)l, 16, 0, 0);
}

// XCD-chunked bijective remap (valid when (gridDim.x*gridDim.y) % 8 == 0).
__device__ __forceinline__ void xcd_swizzle(int& bx, int& by) {
  const int gx = gridDim.x, nxy = gx * gridDim.y;
  const int oid = blockIdx.y * gx + blockIdx.x;
  const int nid = (oid & 7) * (nxy >> 3) + (oid >> 3);
  bx = nid % gx;
  by = nid / gx;
}

// Fused prep: z=0 -> cast x f32->bf16; z=1 -> transpose+cast the three W.
__global__ __launch_bounds__(256)
void prep(const float* __restrict__ x, short* __restrict__ Xb,
          const float* __restrict__ W0, const float* __restrict__ W1,
          const float* __restrict__ W2,
          short* __restrict__ T0, short* __restrict__ T1, short* __restrict__ T2) {
  __shared__ float tile[32][33];
  const int t = threadIdx.x;
  if (blockIdx.z == 0) {
    int i = (blockIdx.x * 256 + t) * 4;   // grid.x = 6144 covers MS*D_ exactly
    float4v v = *(const float4v*)(x + i);
    short4v o;
    o.x = f2bf(v.x); o.y = f2bf(v.y); o.z = f2bf(v.z); o.w = f2bf(v.w);
    *(short4v*)(Xb + i) = o;
  } else {
    int wid = blockIdx.x;
    if (wid >= 1728) return;              // 24*24*3
    int wz = wid / 576, rem = wid - wz * 576;
    int wy = rem / 24, wx = rem - wy * 24;
    const float* W = wz == 0 ? W0 : (wz == 1 ? W1 : W2);
    short* T = wz == 0 ? T0 : (wz == 1 ? T1 : T2);
    int bx = wx * 32, by = wy * 32;
    int tx = t & 31, ty = t >> 5;
    for (int r = ty; r < 32; r += 8)
      tile[r][tx] = W[(by + r) * D_ + bx + tx];
    __syncthreads();
    for (int r = ty; r < 32; r += 8)
      T[(bx + r) * D_ + by + tx] = f2bf(tile[tx][r]);
  }
}

// ---------------------------------------------------------------------------
// 128x128 2-phase kernel — QKV tri-output only.
// ---------------------------------------------------------------------------
template<int TM, int TN>
__global__ __launch_bounds__(256)
void gemm_bt(const short* __restrict__ A, const short* __restrict__ Bt,
             short* __restrict__ C0, short* __restrict__ C1, short* __restrict__ C2,
             const float* __restrict__ bias0, const float* __restrict__ bias1,
             const float* __restrict__ bias2,
             int K, int lda, int ldb) {
  constexpr int BMv = TM * 32, BNv = TN * 32;

  __shared__ short As[BMv * 64];
  __shared__ short Bs[BNv * 64];

  const int t = threadIdx.x;
  const int wave = t >> 6, lane = t & 63;
  const int lane16 = lane & 15, q = lane >> 4;
  int bxs, bys;
  xcd_swizzle(bxs, bys);
  const int m0 = bys * BMv, n0 = bxs * BNv;
  const int wm = (wave >> 1) * (TM * 16), wn = (wave & 1) * (TN * 16);
  const int rsub = lane >> 3;
  const int g = (lane & 7) ^ rsub;

  auto stage = [&](int kk) {
#pragma unroll
    for (int i = wave; i < BMv / 8; i += 4)
      glds16(A + (long)(m0 + i * 8 + rsub) * lda + kk + g * 8, &As[i * 512]);
#pragma unroll
    for (int i = wave; i < BNv / 8; i += 4)
      glds16(Bt + (long)(n0 + i * 8 + rsub) * ldb + kk + g * 8, &Bs[i * 512]);
  };

  stage(0);

  float4v acc[TM][TN];
#pragma unroll
  for (int i = 0; i < TM; i++)
#pragma unroll
    for (int j = 0; j < TN; j++) acc[i][j] = {0.f, 0.f, 0.f, 0.f};

  for (int k0 = 0; k0 < K; k0 += 64) {
    __syncthreads();  // B1: drains stage(k0) [vmcnt(0)] + wave sync

    short8 af[2][TM], bfr[2][TN];
#pragma unroll
    for (int s = 0; s < 2; s++) {
#pragma unroll
      for (int i = 0; i < TM; i++) {
        int R = wm + i * 16 + lane16;
        af[s][i] = *(const short8*)&As[R * 64 + (((s * 4 + q) ^ (R & 7)) * 8)];
      }
#pragma unroll
      for (int j = 0; j < TN; j++) {
        int R = wn + j * 16 + lane16;
        bfr[s][j] = *(const short8*)&Bs[R * 64 + (((s * 4 + q) ^ (R & 7)) * 8)];
      }
    }
    __syncthreads();  // B2: all waves done reading LDS

    if (k0 + 64 < K) stage(k0 + 64);  // async; overlaps the MFMA pack below

#pragma unroll
    for (int s = 0; s < 2; s++)
#pragma unroll
      for (int i = 0; i < TM; i++)
#pragma unroll
        for (int j = 0; j < TN; j++)
          acc[i][j] = __builtin_amdgcn_mfma_f32_16x16x32_bf16(af[s][i], bfr[s][j], acc[i][j], 0, 0, 0);
  }

#pragma unroll
  for (int i = 0; i < TM; i++) {
    int mrow = m0 + wm + i * 16 + q * 4;
#pragma unroll
    for (int j = 0; j < TN; j++) {
      int ncol = n0 + wn + j * 16 + lane16;   // tile-uniform branch: bounds %16
      if (ncol < 1536) {
        short* dst = ncol < 768 ? C0 : C1;
        const float* bs = ncol < 768 ? bias0 : bias1;
        int c = ncol < 768 ? ncol : ncol - 768;   // NOT `& 767` (768 != pow2)
#pragma unroll
        for (int rr = 0; rr < 4; rr++)
          dst[(long)(mrow + rr) * 768 + c] = f2bf(acc[i][j][rr] + bs[c]);
      } else {
        int e = ncol - 1536;
        float bv = bias2[e];
        short4v o;
#pragma unroll
        for (int rr = 0; rr < 4; rr++) o[rr] = f2bf(acc[i][j][rr] + bv);
        *(short4v*)&C2[(long)e * MS + mrow] = o;   // Vt[e][m], 8-B store
      }
    }
  }
}

// ---------------------------------------------------------------------------
// Fused attention v2. Block = (batch, 32-q-row tile) = 256 blocks, 512 thr.
// S stage: KVBLK=256, d-loop 12 x BK=64 (K glds16-staged dbuf, 2-phase).
//   Wave w owns kv cols [w*32, w*32+32): 8 MFMA / d-iter.
// P = exp(S*scale) -> Ps[32][256] bf16, granule-XOR swizzled.
// PV (O^T): A = V (rows e, per-lane contiguous 16B global), B = P (LDS).
//   Wave w owns e rows [w*96, w*96+96): 12 MFMA / chunk, 8 chunks/tile.
// Pipeline: d-loop of tile tt interleaves PV chunks of tile tt-1.
// ---------------------------------------------------------------------------
__global__ __launch_bounds__(512, 2)
void fused_attn2(const short* __restrict__ Qb, const short* __restrict__ Kb,
                 const short* __restrict__ Vt, float* __restrict__ out,
                 float scale) {
  const int x = blockIdx.x;
  const int xcd = x & 7, kblk = x >> 3;
  const int b = xcd >> 1;
  const int q0 = ((kblk << 1) | (xcd & 1)) * 32;

  __shared__ short Qs[12 * 32 * 64];   // 48 KiB: 12 d-chunks x [32 r][64]
  __shared__ short Ks[2][256 * 64];    // 64 KiB: dbuf [256 kv][64]
  __shared__ short Ps[32 * 256];       // 16 KiB: [32 q][256 kv] swizzled

  const int t = threadIdx.x;
  const int wave = t >> 6, lane = t & 63;
  const int lane16 = lane & 15, q = lane >> 4;
  const int rsub = lane >> 3;
  const int g = (lane & 7) ^ rsub;

  // ---- stage Q: 12 chunks x 4 rowblocks = 48 glds16, 6 per wave ----
  {
    const short* qsrc = Qb + (long)(b * 2048 + q0) * 768;
#pragma unroll
    for (int i = 0; i < 6; i++) {
      int id = wave + 8 * i;           // 0..47
      int ch = id >> 2, rb = id & 3;
      glds16(qsrc + (long)(rb * 8 + rsub) * 768 + ch * 64 + g * 8,
             &Qs[ch * 2048 + rb * 512]);
    }
  }

  const short* kbb = Kb + (long)(b * 2048) * 768;
  auto stageK = [&](int buf, int kv0, int ch) {
#pragma unroll
    for (int j = 0; j < 4; j++) {
      int i = wave + 8 * j;            // rowblock 0..31
      glds16(kbb + (long)(kv0 + i * 8 + rsub) * 768 + ch * 64 + g * 8,
             &Ks[buf][i * 512]);
    }
  };
  stageK(0, 0, 0);

  float4v acc_o[6][2];
#pragma unroll
  for (int m = 0; m < 6; m++)
#pragma unroll
    for (int n = 0; n < 2; n++) acc_o[m][n] = {0.f, 0.f, 0.f, 0.f};
  float4v acc_rs[2];
  acc_rs[0] = {0.f, 0.f, 0.f, 0.f};
  acc_rs[1] = {0.f, 0.f, 0.f, 0.f};
  short8 ones;
#pragma unroll
  for (int e = 0; e < 8; e++) ones[e] = (short)0x3F80;  // bf16 1.0

  const short* vbb = Vt + (long)b * 2048;

  int cur = 0;
  for (int tt = 0; tt <= 8; ++tt) {
    const int kvp = (tt - 1) * 256;    // PV tile (valid for tt>=1)
    if (tt < 8) {
      const int kv0 = tt * 256;
      float4v sAcc[2][2];
#pragma unroll
      for (int m = 0; m < 2; m++)
#pragma unroll
        for (int n = 0; n < 2; n++) sAcc[m][n] = {0.f, 0.f, 0.f, 0.f};

      for (int ch = 0; ch < 12; ++ch) {
        __syncthreads();               // drains K stage (+Q at tt=0,ch=0)
        short8 a[2][2], bf[2][2];
#pragma unroll
        for (int m = 0; m < 2; m++) {
          int R = m * 16 + lane16;
#pragma unroll
          for (int s = 0; s < 2; s++)
            a[m][s] = *(const short8*)&Qs[ch * 2048 + R * 64 + (((s * 4 + q) ^ (R & 7)) * 8)];
        }
#pragma unroll
        for (int n = 0; n < 2; n++) {
          int R = wave * 32 + n * 16 + lane16;
#pragma unroll
          for (int s = 0; s < 2; s++)
            bf[n][s] = *(const short8*)&Ks[cur][R * 64 + (((s * 4 + q) ^ (R & 7)) * 8)];
        }
        __syncthreads();               // buffer free for restage
        if (ch < 11) stageK(cur ^ 1, kv0, ch + 1);
        else if (tt + 1 < 8) stageK(cur ^ 1, kv0 + 256, 0);

        if (tt >= 1 && ch < 8) {
          // PV chunk ch of tile tt-1: issue V loads early, MFMA after S
          short8 va[6], pb[2];
#pragma unroll
          for (int m = 0; m < 6; m++) {
            int e = wave * 96 + m * 16 + lane16;
            va[m] = *(const short8*)&vbb[(long)e * 8192 + kvp + ch * 32 + q * 8];
          }
#pragma unroll
          for (int n = 0; n < 2; n++) {
            int R = n * 16 + lane16;
            pb[n] = *(const short8*)&Ps[R * 256 + (((ch * 4 + q) ^ (R & 7)) * 8)];
          }
#pragma unroll
          for (int s = 0; s < 2; s++)
#pragma unroll
            for (int m = 0; m < 2; m++)
#pragma unroll
              for (int n = 0; n < 2; n++)
                sAcc[m][n] = __builtin_amdgcn_mfma_f32_16x16x32_bf16(a[m][s], bf[n][s], sAcc[m][n], 0, 0, 0);
          if (wave == 0) {
            acc_rs[0] = __builtin_amdgcn_mfma_f32_16x16x32_bf16(ones, pb[0], acc_rs[0], 0, 0, 0);
            acc_rs[1] = __builtin_amdgcn_mfma_f32_16x16x32_bf16(ones, pb[1], acc_rs[1], 0, 0, 0);
          }
#pragma unroll
          for (int m = 0; m < 6; m++)
#pragma unroll
            for (int n = 0; n < 2; n++)
              acc_o[m][n] = __builtin_amdgcn_mfma_f32_16x16x32_bf16(va[m], pb[n], acc_o[m][n], 0, 0, 0);
        } else {
#pragma unroll
          for (int s = 0; s < 2; s++)
#pragma unroll
            for (int m = 0; m < 2; m++)
#pragma unroll
              for (int n = 0; n < 2; n++)
                sAcc[m][n] = __builtin_amdgcn_mfma_f32_16x16x32_bf16(a[m][s], bf[n][s], sAcc[m][n], 0, 0, 0);
        }
        cur ^= 1;
      }

      // P(tt) = exp(S*scale) -> Ps (safe: all PV reads of tile tt-1 ended
      // >= 4 barriers ago; next readers sync first)
#pragma unroll
      for (int m = 0; m < 2; m++)
#pragma unroll
        for (int n = 0; n < 2; n++)
#pragma unroll
          for (int rr = 0; rr < 4; rr++) {
            int row = m * 16 + q * 4 + rr;
            int c = wave * 32 + n * 16 + lane16;
            int gr = (c >> 3) ^ (row & 7);
            Ps[row * 256 + gr * 8 + (c & 7)] = f2bf(__expf(sAcc[m][n][rr] * scale));
          }
    } else {
      // tt == 8: standalone PV of tile 7
      __syncthreads();                 // Ps(7) visible
#pragma unroll
      for (int ch = 0; ch < 8; ++ch) {
        short8 va[6], pb[2];
#pragma unroll
        for (int m = 0; m < 6; m++) {
          int e = wave * 96 + m * 16 + lane16;
          va[m] = *(const short8*)&vbb[(long)e * 8192 + kvp + ch * 32 + q * 8];
        }
#pragma unroll
        for (int n = 0; n < 2; n++) {
          int R = n * 16 + lane16;
          pb[n] = *(const short8*)&Ps[R * 256 + (((ch * 4 + q) ^ (R & 7)) * 8)];
        }
        if (wave == 0) {
          acc_rs[0] = __builtin_amdgcn_mfma_f32_16x16x32_bf16(ones, pb[0], acc_rs[0], 0, 0, 0);
          acc_rs[1] = __builtin_amdgcn_mfma_f32_16x16x32_bf16(ones, pb[1], acc_rs[1], 0, 0, 0);
        }
#pragma unroll
        for (int m = 0; m < 6; m++)
#pragma unroll
          for (int n = 0; n < 2; n++)
            acc_o[m][n] = __builtin_amdgcn_mfma_f32_16x16x32_bf16(va[m], pb[n], acc_o[m][n], 0, 0, 0);
      }
    }
  }

  // ---- rowsums (wave 0) -> reuse Ps as float scratch; divide + store ----
  __syncthreads();                     // PV(7) reads of Ps done everywhere
  float* rsf = (float*)&Ps[0];
  if (wave == 0 && lane < 16) {
    rsf[lane] = acc_rs[0][0];          // q tokens 0..15 (C/D col = lane16)
    rsf[16 + lane] = acc_rs[1][0];     // q tokens 16..31
  }
  __syncthreads();

  float* ob = out + (long)(b * 2048 + q0) * 768;
#pragma unroll
  for (int n = 0; n < 2; n++) {
    int qcol = n * 16 + lane16;
    float inv = 1.0f / rsf[qcol];
#pragma unroll
    for (int m = 0; m < 6; m++) {
      int e0 = wave * 96 + m * 16 + q * 4;
      float4v o;
#pragma unroll
      for (int rr = 0; rr < 4; rr++) o[rr] = acc_o[m][n][rr] * inv;
      *(float4v*)&ob[(long)qcol * 768 + e0] = o;   // 16-B aligned
    }
  }
}

extern "C" void kernel_launch(void* const* d_in, const int* in_sizes, int n_in,
                              void* d_out, int out_size, void* d_ws, size_t ws_size,
                              hipStream_t stream) {
  const float* x  = (const float*)d_in[0];
  const float* Wq = (const float*)d_in[1];
  const float* bq = (const float*)d_in[2];
  const float* Wk = (const float*)d_in[3];
  const float* bk = (const float*)d_in[4];
  const float* Wv = (const float*)d_in[5];
  const float* bv = (const float*)d_in[6];
  float* out = (float*)d_out;

  short* Xb  = (short*)d_ws;                     // [8192][768]
  short* WqT = Xb + (long)MS * D_;               // [2304][768] = WqT||WkT||WvT
  short* WkT = WqT + (long)D_ * D_;
  short* WvT = WkT + (long)D_ * D_;
  short* Qb  = WvT + (long)D_ * D_;              // [8192][768]
  short* Kb  = Qb + (long)MS * D_;               // [8192][768]
  short* Vt  = Kb + (long)MS * D_;               // [768][8192]

  // Fused prep: cast x (z=0) + transpose/cast W (z=1)
  prep<<<dim3(6144, 1, 2), 256, 0, stream>>>(x, Xb, Wq, Wk, Wv, WqT, WkT, WvT);

  // Q||K||Vt = Xb @ [WqT;WkT;WvT]^T + biases  (128x128 2-phase, 18x64 blk)
  gemm_bt<4, 4><<<dim3(2304 / 128, MS / 128, 1), 256, 0, stream>>>(
      Xb, WqT, Qb, Kb, Vt, bq, bk, bv, D_, D_, D_);

  // Fused attention v2: 256 blocks (perfect CU fit), 512 threads
  fused_attn2<<<dim3(256, 1, 1), 512, 0, stream>>>(
      Qb, Kb, Vt, out, 1.0f / sqrtf((float)D_));
}